// Round 9
// baseline (3880.113 us; speedup 1.0000x reference)
//
#include <hip/hip_runtime.h>
#include <cmath>

typedef unsigned short u16;
typedef unsigned int u32;
typedef unsigned long long u64;
typedef __attribute__((ext_vector_type(8))) short s16x8;
typedef __attribute__((ext_vector_type(8))) unsigned short u16x8;
typedef __attribute__((ext_vector_type(4))) unsigned short u16x4;
typedef __attribute__((ext_vector_type(4))) float f32x4;

#define LN_EPS 1e-6f
#define SCOPE_AGENT __HIP_MEMORY_SCOPE_AGENT

// ---------- helpers ----------
__device__ __forceinline__ u16 f2bf(float f) {
  union { float f; u32 u; } v; v.f = f;
  u32 r = v.u + 0x7FFFu + ((v.u >> 16) & 1u);
  return (u16)(r >> 16);
}
__device__ __forceinline__ float bf2f(u16 h) {
  union { u32 u; float f; } v; v.u = ((u32)h) << 16; return v.f;
}

__device__ __forceinline__ void astore64(u64* p, u64 v) {
  __hip_atomic_store(p, v, __ATOMIC_RELAXED, SCOPE_AGENT);
}

__device__ __forceinline__ void gload_lds16(const void* g, void* l) {
  __builtin_amdgcn_global_load_lds(
      (__attribute__((address_space(1))) void*)g,
      (__attribute__((address_space(3))) void*)l, 16, 0, 0);
}

__device__ __forceinline__ f32x4 mfma16(s16x8 a, s16x8 b, f32x4 c) {
  return __builtin_amdgcn_mfma_f32_16x16x32_bf16(a, b, c, 0, 0, 0);
}

// ---------- kernel 1: Xc[m][2048] = bf16(concat(inputo, attn)), m=b*Tc+tc ----------
__global__ __launch_bounds__(256) void cvtx_kernel(const float* __restrict__ inputo,
                                                   const float* __restrict__ attn,
                                                   u16* __restrict__ Xc,
                                                   int t0, int log2Tc) {
  size_t i = ((size_t)blockIdx.x * 256 + threadIdx.x) * 4;
  size_t m = i >> 10, d = i & 1023;
  int tc = (int)(m & ((1u << log2Tc) - 1));
  int b  = (int)(m >> log2Tc);
  size_t src = ((size_t)b * 256 + t0 + tc) * 1024 + d;
  float4 a = *(const float4*)(inputo + src);
  float4 v = *(const float4*)(attn + src);
  u16x4 va = { f2bf(a.x), f2bf(a.y), f2bf(a.z), f2bf(a.w) };
  u16x4 vb = { f2bf(v.x), f2bf(v.y), f2bf(v.z), f2bf(v.w) };
  *(u16x4*)(Xc + m * 2048 + d) = va;
  *(u16x4*)(Xc + m * 2048 + 1024 + d) = vb;
}

// ---------- kernel 2: WT[n][k] = bf16(W[k][n]) ----------
__global__ __launch_bounds__(256) void wtrans_kernel(const float* __restrict__ W,
                                                     u16* __restrict__ WT) {
  __shared__ float tile[32][33];
  int bn = blockIdx.x & 127;
  int bk = blockIdx.x >> 7;
  int n0 = bn * 32, k0 = bk * 32;
  int tx = threadIdx.x & 31, ty = threadIdx.x >> 5;
#pragma unroll
  for (int i = 0; i < 32; i += 8)
    tile[ty + i][tx] = W[(size_t)(k0 + ty + i) * 4096 + n0 + tx];
  __syncthreads();
#pragma unroll
  for (int i = 0; i < 32; i += 8)
    WT[(size_t)(n0 + ty + i) * 3072 + k0 + tx] = f2bf(tile[tx][ty + i]);
}

// ---------- kernel 3: init tagged hx bufs, cx, tagged gpart ----------
// hxT pairs: [buf(2)][row(64)][fp(512)] u64 = (tag<<32)|(2xbf16). buf1 holds
// hx(-1)=init_hx with tag 0 (stage(0) expects tag>=0); buf0 tag 0 (stale for
// expected tag>=1). gpT: [buf(2)][mach(4)][tg(32)][slot(64)] u64, tags 0.
__global__ __launch_bounds__(256) void init_kernel(const float* __restrict__ init_hx,
                                                   const float* __restrict__ init_cx,
                                                   u64* __restrict__ hxT,
                                                   float* __restrict__ cxbuf,
                                                   u64* __restrict__ gpT) {
  int i = blockIdx.x * 256 + threadIdx.x; // 65536 threads
  if (i < 32768) {
    int fp = i & 511;
    u32 pack = (u32)f2bf(init_hx[fp * 2]) | ((u32)f2bf(init_hx[fp * 2 + 1]) << 16);
    hxT[32768 + i] = (u64)pack; // buf1, tag 0
    hxT[i] = 0ull;              // buf0, tag 0
  }
  cxbuf[i] = init_cx[i & 1023];
  if (i < 16384) gpT[i] = 0ull;
}

// ---------- kernel 4: Zxc[m][n] = bf16( sum_k Xc[m][k]*WT[n][k] ) ----------
__global__ __launch_bounds__(256) void gemm_zx_kernel(const u16* __restrict__ Xc,
                                                      const u16* __restrict__ WT,
                                                      u16* __restrict__ Zxc,
                                                      int log2nmt) {
  __shared__ u16 As[128 * 64];
  __shared__ u16 Bs[128 * 64];
  const int tid = threadIdx.x, lane = tid & 63, wave = tid >> 6;
  const int nmt_mask = (1 << log2nmt) - 1;
  int mt = blockIdx.x & nmt_mask;
  int nt = blockIdx.x >> log2nmt;
  const size_t m0 = (size_t)mt * 128, n0 = (size_t)nt * 128;
  const int wm = (wave >> 1) * 64, wn = (wave & 1) * 64;
  const int l15 = lane & 15, kg = lane >> 4;
  const int s_r = lane >> 3;
  const int s_c = (lane & 7) * 8;

  f32x4 acc[4][4];
#pragma unroll
  for (int a = 0; a < 4; ++a)
#pragma unroll
    for (int b = 0; b < 4; ++b) acc[a][b] = (f32x4){0.f, 0.f, 0.f, 0.f};

  for (int k0 = 0; k0 < 2048; k0 += 64) {
#pragma unroll
    for (int it = 0; it < 4; ++it) {
      int ch = (wave << 2) + it;
      int row = (ch << 3) + s_r;
      gload_lds16(Xc + (m0 + row) * 2048 + k0 + s_c, (char*)As + (ch << 10));
      gload_lds16(WT + (n0 + row) * 3072 + k0 + s_c, (char*)Bs + (ch << 10));
    }
    __syncthreads();
#pragma unroll
    for (int kk = 0; kk < 2; ++kk) {
      s16x8 af[4], bf[4];
#pragma unroll
      for (int i = 0; i < 4; ++i)
        af[i] = *(const s16x8*)(As + (wm + i * 16 + l15) * 64 + kk * 32 + kg * 8);
#pragma unroll
      for (int i = 0; i < 4; ++i)
        bf[i] = *(const s16x8*)(Bs + (wn + i * 16 + l15) * 64 + kk * 32 + kg * 8);
#pragma unroll
      for (int mi = 0; mi < 4; ++mi)
#pragma unroll
        for (int ni = 0; ni < 4; ++ni)
          acc[mi][ni] = mfma16(af[mi], bf[ni], acc[mi][ni]);
    }
    __syncthreads();
  }
#pragma unroll
  for (int ni = 0; ni < 4; ++ni) {
    size_t n = n0 + wn + ni * 16 + l15;
#pragma unroll
    for (int mi = 0; mi < 4; ++mi) {
#pragma unroll
      for (int j = 0; j < 4; ++j) {
        size_t m = m0 + wm + mi * 16 + (kg << 2) + j;
        Zxc[m * 4096 + n] = f2bf(acc[mi][ni][j]);
      }
    }
  }
}

// ---------- kernel 5: persistent recurrence, BARRIER-FREE tagged protocol ----------
// 4 machines x 64 wgs; wg = 16 features x 4 gates; wave = 1 gate, M=16 tile.
// hx(t):  hxT[t&1][row][fp] = (tag=t+1, 2xbf16).  stage(t) polls buf[(t+1)&1]
//         for tags >= t (gates(t-1) wrote tag t).
// stats(t): gpT[t&1][mach][tg][slot] = (tag=t+1, float). reduce(t) polls ALL
//         64 slots for tags >= t+1 (this completeness is also what makes
//         buffer reuse at t+2 race-free: gates(t+1) anywhere implies every
//         wg posted gpart(t+1), which is program-order after its stage(t)).
__global__ __launch_bounds__(256, 1) void recurrent_kernel(
    const u16* __restrict__ Zxc, const u16* __restrict__ WT,
    const float* __restrict__ inputo, const float* __restrict__ bias,
    const float* __restrict__ ln_w, const float* __restrict__ ln_b,
    float* __restrict__ out, u64* __restrict__ hxT, float* __restrict__ cxbuf,
    u64* __restrict__ gpT, int t0, int log2Tc) {
  __shared__ __align__(16) u16 hxS[16 * 1024]; // [row][16B slot k8p=k8^(row&7)]
  __shared__ __align__(16) u16 zxS[16 * 64];
  __shared__ float zbuf[16][68];
  __shared__ float spart[4][32];
  __shared__ float stot[16][2];

  const int Tc = 1 << log2Tc;
  const int tid = threadIdx.x, lane = tid & 63, wv = tid >> 6;
  const int mach = blockIdx.x >> 6, slot = blockIdx.x & 63;
  const int f0 = slot << 4;
  const int l15 = lane & 15, kg = lane >> 4;
  const int ncol = (wv << 10) + f0 + l15;
  const float lnw = ln_w[ncol], lnb = ln_b[ncol], bz = bias[ncol];

  // Wh B-fragments in VGPRs
  s16x8 bfrag[32];
  {
    const u16* bp = WT + (size_t)ncol * 3072 + 2048 + (kg << 3);
#pragma unroll
    for (int kb = 0; kb < 32; ++kb) bfrag[kb] = *(const s16x8*)(bp + (kb << 5));
  }

  // gates-phase role (tid<128): row grow, feature pair
  const int grow = tid >> 3, gfp = (tid & 7) << 1;
  const int gb = (mach << 4) + grow;
  const int gd = f0 + gfp;
  const int gfpair = (slot << 3) + (tid & 7); // fp = gd>>1
  float2 cx = {0.f, 0.f};
  if (tid < 128) cx = *(const float2*)(cxbuf + gb * 1024 + gd);

  // hx poll voffsets: chunk c = it*256+tid, byte = c*16
  const u32 vo0 = (u32)tid << 4;
  const u32 vo1 = vo0 + 4096,  vo2 = vo0 + 8192,   vo3 = vo0 + 12288;
  const u32 vo4 = vo0 + 16384, vo5 = vo0 + 20480,  vo6 = vo0 + 24576;
  const u32 vo7 = vo0 + 28672, vo8 = vo0 + 32768,  vo9 = vo0 + 36864;
  const u32 voA = vo0 + 40960, voB = vo0 + 45056,  voC = vo0 + 49152;
  const u32 voD = vo0 + 53248, voE = vo0 + 57344,  voF = vo0 + 61440;
  const int sl = tid >> 1, hf = (tid & 1) << 2; // ds_write slot/half (u16 units)
  // gpart reduce role: tg = tid>>3, seg = tid&7; each seg = 8 slots = 64B
  const u32 gvo = (((u32)tid >> 3) << 9) | (((u32)tid & 7) << 6);

  const u64* hxM = hxT + ((size_t)mach << 13);        // + bufsel*32768
  const u64* gpM = gpT + ((size_t)mach << 11);        // + bufsel*8192
  u64* gpWr = gpT + ((size_t)mach << 11) + slot;      // + bufsel*8192 + tg*64
  u64* hxWr = hxT + (size_t)gb * 512 + gfpair;        // + bufsel*32768

  for (int tc = 0; tc < Tc; ++tc) {
    const int t = t0 + tc;

    // ---- issue Zx slice stage (independent of polls)
    if (tid < 128) {
      int row = tid >> 3, q = tid & 7, gate = q >> 1, hh = q & 1;
      size_t m = ((size_t)((mach << 4) + row) << log2Tc) + tc;
      gload_lds16(Zxc + m * 4096 + ((size_t)gate << 10) + f0 + (hh << 3),
                  (char*)zxS + (tid << 4));
    }
    float2 inv = {0.f, 0.f};
    if (tid < 128) inv = *(const float2*)(inputo + ((size_t)gb * 256 + t) * 1024 + gd);

    // ---- hx tagged poll: 16 x dwordx4 (row it, chunk tid), all in flight
    f32x4 h0, h1, h2, h3, h4, h5, h6, h7, h8, h9, hA, hB, hC, hD, hE, hF;
    {
      const void* hp = (const void*)(hxM + (((size_t)(t + 1) & 1) << 15));
      const u32 exp = (u32)t;
      for (;;) {
        asm volatile(
            "global_load_dwordx4 %0, %16, %32 sc0 sc1\n\t"
            "global_load_dwordx4 %1, %17, %32 sc0 sc1\n\t"
            "global_load_dwordx4 %2, %18, %32 sc0 sc1\n\t"
            "global_load_dwordx4 %3, %19, %32 sc0 sc1\n\t"
            "global_load_dwordx4 %4, %20, %32 sc0 sc1\n\t"
            "global_load_dwordx4 %5, %21, %32 sc0 sc1\n\t"
            "global_load_dwordx4 %6, %22, %32 sc0 sc1\n\t"
            "global_load_dwordx4 %7, %23, %32 sc0 sc1\n\t"
            "global_load_dwordx4 %8, %24, %32 sc0 sc1\n\t"
            "global_load_dwordx4 %9, %25, %32 sc0 sc1\n\t"
            "global_load_dwordx4 %10, %26, %32 sc0 sc1\n\t"
            "global_load_dwordx4 %11, %27, %32 sc0 sc1\n\t"
            "global_load_dwordx4 %12, %28, %32 sc0 sc1\n\t"
            "global_load_dwordx4 %13, %29, %32 sc0 sc1\n\t"
            "global_load_dwordx4 %14, %30, %32 sc0 sc1\n\t"
            "global_load_dwordx4 %15, %31, %32 sc0 sc1\n\t"
            "s_waitcnt vmcnt(0)"
            : "=&v"(h0), "=&v"(h1), "=&v"(h2), "=&v"(h3),
              "=&v"(h4), "=&v"(h5), "=&v"(h6), "=&v"(h7),
              "=&v"(h8), "=&v"(h9), "=&v"(hA), "=&v"(hB),
              "=&v"(hC), "=&v"(hD), "=&v"(hE), "=&v"(hF)
            : "v"(vo0), "v"(vo1), "v"(vo2), "v"(vo3),
              "v"(vo4), "v"(vo5), "v"(vo6), "v"(vo7),
              "v"(vo8), "v"(vo9), "v"(voA), "v"(voB),
              "v"(voC), "v"(voD), "v"(voE), "v"(voF), "s"(hp)
            : "memory");
        bool ok = true;
#define TCHK(HV) ok = ok & (__float_as_uint((HV)[1]) >= exp) & (__float_as_uint((HV)[3]) >= exp)
        TCHK(h0); TCHK(h1); TCHK(h2); TCHK(h3); TCHK(h4); TCHK(h5); TCHK(h6); TCHK(h7);
        TCHK(h8); TCHK(h9); TCHK(hA); TCHK(hB); TCHK(hC); TCHK(hD); TCHK(hE); TCHK(hF);
#undef TCHK
        if (__all(ok)) break;
        __builtin_amdgcn_s_sleep(1);
      }
    }
    // ---- strip tags -> swizzled LDS (row=it, chunk cc=tid)
#define DSW(IT, HV) \
    *(u64*)(hxS + (IT) * 1024 + ((sl ^ ((IT) & 7)) << 3) + hf) = \
        ((u64)__float_as_uint((HV)[2]) << 32) | (u64)__float_as_uint((HV)[0]);
    DSW(0, h0)  DSW(1, h1)  DSW(2, h2)  DSW(3, h3)
    DSW(4, h4)  DSW(5, h5)  DSW(6, h6)  DSW(7, h7)
    DSW(8, h8)  DSW(9, h9)  DSW(10, hA) DSW(11, hB)
    DSW(12, hC) DSW(13, hD) DSW(14, hE) DSW(15, hF)
#undef DSW
    __syncthreads(); // S1: hxS + zxS ready

    // ---- GEMM: 16 rows x 16 cols per wave, K=1024, 2 independent chains
    f32x4 aca = (f32x4){0.f, 0.f, 0.f, 0.f};
    f32x4 acb = (f32x4){0.f, 0.f, 0.f, 0.f};
#pragma unroll
    for (int kb = 0; kb < 16; ++kb) {
      int k8a = (kb << 2) | kg;
      int k8b = ((kb + 16) << 2) | kg;
      s16x8 a0 = *(const s16x8*)(hxS + (l15 << 10) + ((k8a ^ (l15 & 7)) << 3));
      s16x8 a1 = *(const s16x8*)(hxS + (l15 << 10) + ((k8b ^ (l15 & 7)) << 3));
      aca = mfma16(a0, bfrag[kb], aca);
      acb = mfma16(a1, bfrag[kb + 16], acb);
    }

    // ---- z = acc + zx + bias; per-row partial stats
    float z[4], s1[4], s2[4];
#pragma unroll
    for (int j = 0; j < 4; ++j) {
      int row = (kg << 2) + j;
      float zx = bf2f(zxS[(row << 6) + (wv << 4) + l15]);
      z[j] = (aca[j] + acb[j]) + zx + bz;
      s1[j] = z[j];
      s2[j] = z[j] * z[j];
    }
#pragma unroll
    for (int off = 1; off < 16; off <<= 1) {
#pragma unroll
      for (int j = 0; j < 4; ++j) {
        s1[j] += __shfl_xor(s1[j], off, 64);
        s2[j] += __shfl_xor(s2[j], off, 64);
      }
    }
    if (l15 == 0) {
#pragma unroll
      for (int j = 0; j < 4; ++j) {
        int row = (kg << 2) + j;
        spart[wv][(row << 1) + 0] = s1[j];
        spart[wv][(row << 1) + 1] = s2[j];
      }
    }
    __syncthreads(); // S2
    if (tid < 32) { // tg = tid; tagged store (tag=t+1)
      float sv = spart[0][tid] + spart[1][tid] + spart[2][tid] + spart[3][tid];
      astore64(gpWr + (((size_t)(t & 1)) << 13) + (tid << 6),
               ((u64)(u32)(t + 1) << 32) | (u64)__float_as_uint(sv));
    }

    // ---- tagged stats reduce: 256 threads x 8 slots each (tg=tid>>3, seg=tid&7)
    {
      const void* gpb = (const void*)(gpM + (((size_t)(t & 1)) << 13));
      const u32 exp2 = (u32)(t + 1);
      f32x4 g0, g1, g2, g3;
      for (;;) {
        asm volatile(
            "global_load_dwordx4 %0, %4, %5 sc0 sc1\n\t"
            "global_load_dwordx4 %1, %4, %5 offset:16 sc0 sc1\n\t"
            "global_load_dwordx4 %2, %4, %5 offset:32 sc0 sc1\n\t"
            "global_load_dwordx4 %3, %4, %5 offset:48 sc0 sc1\n\t"
            "s_waitcnt vmcnt(0)"
            : "=&v"(g0), "=&v"(g1), "=&v"(g2), "=&v"(g3)
            : "v"(gvo), "s"(gpb)
            : "memory");
        bool ok = (__float_as_uint(g0[1]) >= exp2) & (__float_as_uint(g0[3]) >= exp2) &
                  (__float_as_uint(g1[1]) >= exp2) & (__float_as_uint(g1[3]) >= exp2) &
                  (__float_as_uint(g2[1]) >= exp2) & (__float_as_uint(g2[3]) >= exp2) &
                  (__float_as_uint(g3[1]) >= exp2) & (__float_as_uint(g3[3]) >= exp2);
        if (__all(ok)) break;
        __builtin_amdgcn_s_sleep(1);
      }
      float s = ((g0[0] + g0[2]) + (g1[0] + g1[2])) +
                ((g2[0] + g2[2]) + (g3[0] + g3[2]));
      s += __shfl_xor(s, 1, 64);
      s += __shfl_xor(s, 2, 64);
      s += __shfl_xor(s, 4, 64);
      if ((tid & 7) == 0) {
        int tg = tid >> 3;
        stot[tg >> 1][tg & 1] = s;
      }
    }
    __syncthreads(); // S3: stot ready

    // ---- LN -> zbuf
#pragma unroll
    for (int j = 0; j < 4; ++j) {
      int row = (kg << 2) + j;
      float mean = stot[row][0] * (1.f / 4096.f);
      float var = stot[row][1] * (1.f / 4096.f) - mean * mean;
      float rstd = 1.f / sqrtf(var + LN_EPS);
      zbuf[row][(wv << 4) + l15] = (z[j] - mean) * rstd * lnw + lnb;
    }
    __syncthreads(); // S4

    // ---- gates + state update + tagged hx store
    if (tid < 128) {
      float2 zi = *(const float2*)&zbuf[grow][gfp];
      float2 zf = *(const float2*)&zbuf[grow][16 + gfp];
      float2 zo = *(const float2*)&zbuf[grow][32 + gfp];
      float2 zh = *(const float2*)&zbuf[grow][48 + gfp];
      float ig0 = 1.f / (1.f + expf(-zi.x)), ig1 = 1.f / (1.f + expf(-zi.y));
      float fg0 = 1.f / (1.f + expf(-zf.x)), fg1 = 1.f / (1.f + expf(-zf.y));
      float og0 = 1.f / (1.f + expf(-zo.x)), og1 = 1.f / (1.f + expf(-zo.y));
      float h0v = 0.5f * zh.x * (1.f + erff(zh.x * 0.70710678118654752f));
      float h1v = 0.5f * zh.y * (1.f + erff(zh.y * 0.70710678118654752f));
      cx.x = fg0 * cx.x + ig0 * h0v;
      cx.y = fg1 * cx.y + ig1 * h1v;
      float hx0 = og0 * cx.x, hx1 = og1 * cx.y;
      float2 ov = { hx0 + inv.x, hx1 + inv.y };
      *(float2*)(out + ((size_t)gb * 256 + t) * 1024 + gd) = ov;
      u32 hpack = (u32)f2bf(hx0) | ((u32)f2bf(hx1) << 16);
      astore64(hxWr + (((size_t)(t & 1)) << 15),
               ((u64)(u32)(t + 1) << 32) | (u64)hpack);
    }
  }
  if (tid < 128) *(float2*)(cxbuf + gb * 1024 + gd) = cx;
}

// ---------- launch ----------
extern "C" void kernel_launch(void* const* d_in, const int* in_sizes, int n_in,
                              void* d_out, int out_size, void* d_ws, size_t ws_size,
                              hipStream_t stream) {
  const float* inputo  = (const float*)d_in[0];
  const float* attn    = (const float*)d_in[1];
  const float* W       = (const float*)d_in[2];
  const float* bias    = (const float*)d_in[3];
  const float* ln_w    = (const float*)d_in[4];
  const float* ln_b    = (const float*)d_in[5];
  const float* init_hx = (const float*)d_in[6];
  const float* init_cx = (const float*)d_in[7];
  float* out = (float*)d_out;

  const size_t WT_BYTES = (size_t)4096 * 3072 * 2;            // 24 MiB
  const size_t TAIL = 524288 + 262144 + 131072;               // hxT, cx, gpT
  int log2Tc = 7;
  for (; log2Tc > 2; --log2Tc) {
    size_t Tc = (size_t)1 << log2Tc;
    size_t need = WT_BYTES + Tc * 262144 /*Xc*/ + Tc * 524288 /*Zxc*/ + TAIL;
    if (need <= ws_size) break;
  }
  const int Tc = 1 << log2Tc;
  const int nchunks = 256 / Tc;

  char* ws = (char*)d_ws;
  size_t off = 0;
  u16* WT       = (u16*)(ws + off); off += WT_BYTES;
  u16* Xc       = (u16*)(ws + off); off += (size_t)Tc * 262144;
  u16* Zxc      = (u16*)(ws + off); off += (size_t)Tc * 524288;
  u64* hxT      = (u64*)(ws + off); off += 524288;
  float* cxbuf  = (float*)(ws + off); off += 262144;
  u64* gpT      = (u64*)(ws + off);

  wtrans_kernel<<<12288, 256, 0, stream>>>(W, WT);
  init_kernel<<<256, 256, 0, stream>>>(init_hx, init_cx, hxT, cxbuf, gpT);

  for (int c = 0; c < nchunks; ++c) {
    int t0 = c * Tc;
    cvtx_kernel<<<64 * Tc, 256, 0, stream>>>(inputo, attn, Xc, t0, log2Tc);
    gemm_zx_kernel<<<(Tc / 2) * 32, 256, 0, stream>>>(Xc, WT, Zxc, log2Tc - 1);
    recurrent_kernel<<<256, 256, 0, stream>>>(Zxc, WT, inputo, bias, ln_w, ln_b,
                                              out, hxT, cxbuf, gpT, t0, log2Tc);
  }
}